// Round 1
// baseline (611.585 us; speedup 1.0000x reference)
//
#include <hip/hip_runtime.h>
#include <stdint.h>

#define B_  4
#define S_  2048
#define H_  16
#define DH_ 64
#define DM_ 1024

typedef __attribute__((ext_vector_type(8))) short bf16x8;  // 8 bf16 = 4 VGPR
typedef __attribute__((ext_vector_type(4))) float f32x4;

__device__ __forceinline__ ushort f2bf(float x){
  uint32_t u = __float_as_uint(x);
  u += 0x7FFFu + ((u >> 16) & 1u);   // RNE
  return (ushort)(u >> 16);
}
__device__ __forceinline__ uint32_t pack2(float a, float b){
  return (uint32_t)f2bf(a) | ((uint32_t)f2bf(b) << 16);
}
__device__ __forceinline__ f32x4 zero4(){ f32x4 z; z.x=0.f;z.y=0.f;z.z=0.f;z.w=0.f; return z; }

// ---------------------------------------------------------------------------
// W [K][N] fp32  ->  Wt [N][K] bf16   (transpose + convert)
// ---------------------------------------------------------------------------
__global__ __launch_bounds__(256) void wtrans(const float* __restrict__ W,
                                              ushort* __restrict__ Wt){
  __shared__ __align__(16) float t[32][33];
  int n0 = blockIdx.x * 32, k0 = blockIdx.y * 32;
  int col = threadIdx.x & 31, rg = threadIdx.x >> 5;   // 8 row-groups
  #pragma unroll
  for (int i = 0; i < 4; i++){
    int r = rg + i*8;
    t[r][col] = W[(size_t)(k0 + r) * DM_ + n0 + col];
  }
  __syncthreads();
  #pragma unroll
  for (int i = 0; i < 4; i++){
    int r = rg + i*8;                                   // n_local
    Wt[(size_t)(n0 + r) * DM_ + k0 + col] = f2bf(t[col][r]);
  }
}

// ---------------------------------------------------------------------------
// Projection GEMM, 128x128 tile, BK=64, 16x16x32 bf16 MFMA, XOR-swizzled LDS.
// MODE 0 (Q,K): D = Wt_tile * X_tile^T  (m=feature, n=row)  -> out[B,H,S,D]
// MODE 1 (V):   D = X_tile * Wt_tile^T  (m=row, n=feature)  -> out[B,H,D,S]
// ---------------------------------------------------------------------------
template<int MODE>
__global__ __launch_bounds__(256, 2) void gemm_proj(
    const float* __restrict__ X, const ushort* __restrict__ Wt,
    const float* __restrict__ bias, ushort* __restrict__ out)
{
  __shared__ __align__(16) ushort lw[128*64];   // Wt tile [f][k]
  __shared__ __align__(16) ushort lx[128*64];   // X  tile [s][k] (bf16)
  int tid = threadIdx.x;
  int l = tid & 63, w = tid >> 6;
  int ln = l & 15, lq = l >> 4;
  int sbase = blockIdx.x * 128;
  int fbase = blockIdx.y * 128;
  int wm = w >> 1, wn = w & 1;

  f32x4 acc[4][4];
  #pragma unroll
  for (int i=0;i<4;i++)
    #pragma unroll
    for(int j=0;j<4;j++) acc[i][j] = zero4();

  for (int k0 = 0; k0 < DM_; k0 += 64){
    #pragma unroll
    for (int r = 0; r < 4; r++){
      int flat = r*256 + tid;
      int row = flat >> 3, c = flat & 7;
      int g = c ^ (row & 7);                    // XOR swizzle: slot c holds chunk g
      *(uint4*)&lw[row*64 + c*8] =
          *(const uint4*)&Wt[(size_t)(fbase+row)*DM_ + k0 + g*8];
      const float* xs = &X[(size_t)(sbase+row)*DM_ + k0 + g*8];
      float4 x0 = *(const float4*)xs;
      float4 x1 = *(const float4*)(xs+4);
      uint4 p;
      p.x = pack2(x0.x, x0.y); p.y = pack2(x0.z, x0.w);
      p.z = pack2(x1.x, x1.y); p.w = pack2(x1.z, x1.w);
      *(uint4*)&lx[row*64 + c*8] = p;
    }
    __syncthreads();
    const ushort* aS = (MODE==0) ? lw : lx;
    const ushort* bS = (MODE==0) ? lx : lw;
    #pragma unroll
    for (int ks=0; ks<2; ks++){
      bf16x8 af[4], bfr[4];
      #pragma unroll
      for (int i=0;i<4;i++){
        int ar = wm*64 + i*16 + ln;
        int g = ks*4 + lq;
        af[i] = *(const bf16x8*)&aS[ar*64 + (g ^ (ar&7))*8];
      }
      #pragma unroll
      for (int j=0;j<4;j++){
        int br = wn*64 + j*16 + ln;
        int g = ks*4 + lq;
        bfr[j] = *(const bf16x8*)&bS[br*64 + (g ^ (br&7))*8];
      }
      #pragma unroll
      for (int i=0;i<4;i++)
        #pragma unroll
        for (int j=0;j<4;j++)
          acc[i][j] = __builtin_amdgcn_mfma_f32_16x16x32_bf16(af[i], bfr[j], acc[i][j], 0,0,0);
    }
    __syncthreads();
  }

  if (MODE == 0){
    // D[m=f][n=s]; C layout: col=lane&15 -> s, row=(lane>>4)*4+reg -> f
    #pragma unroll
    for (int i=0;i<4;i++){
      int fr = fbase + wm*64 + i*16 + (lq<<2);
      float4 bv = *(const float4*)&bias[fr];
      int h = fr >> 6, d0 = fr & 63;
      #pragma unroll
      for (int j=0;j<4;j++){
        int s = sbase + wn*64 + j*16 + ln;
        int b = s >> 11, sq = s & 2047;
        f32x4 v = acc[i][j];
        uint2 pk;
        pk.x = pack2(v.x + bv.x, v.y + bv.y);
        pk.y = pack2(v.z + bv.z, v.w + bv.w);
        *(uint2*)&out[(((size_t)(b*H_ + h))*S_ + sq)*DH_ + d0] = pk;
      }
    }
  } else {
    // D[m=s][n=f]; col -> f, rows -> s   => Vt[b,h,d,s]
    #pragma unroll
    for (int j=0;j<4;j++){
      int fc = fbase + wn*64 + j*16 + ln;
      float bv = bias[fc];
      int h = fc >> 6, d = fc & 63;
      #pragma unroll
      for (int i=0;i<4;i++){
        int s = sbase + wm*64 + i*16 + (lq<<2);
        int b = s >> 11, sq = s & 2047;
        f32x4 v = acc[i][j];
        uint2 pk;
        pk.x = pack2(v.x + bv, v.y + bv);
        pk.y = pack2(v.z + bv, v.w + bv);
        *(uint2*)&out[(((size_t)(b*H_ + h))*DH_ + d)*S_ + sq] = pk;
      }
    }
  }
}

// ---------------------------------------------------------------------------
// Fused attention. Block = (head h, 64-row q tile), 4 waves.
// MFMA phases: wave = batch b.  Softmax phase: wave = q subtile (all 4 b in-lane).
// S^T = K*Q^T (so kpos lands in regs, q in lanes); softmax over b;
// O^T += V^T * P^T ; epilogue writes O[b, q, h*64+d] fp32.
// ---------------------------------------------------------------------------
__global__ __launch_bounds__(256, 2) void attn(
    const ushort* __restrict__ Q, const ushort* __restrict__ K,
    const ushort* __restrict__ Vt, const float* __restrict__ mask,
    float* __restrict__ out)
{
  __shared__ __align__(16) float  Sl[B_*64*32];   // 32 KB [b][q64][k32] swizzled
  __shared__ __align__(16) ushort Pl[B_*64*32];   // 16 KB [b][q64][k32] bf16 swizzled
  int tid = threadIdx.x;
  int l = tid & 63, w = tid >> 6;
  int ln = l & 15, lq = l >> 4;

  // XCD-aware swizzle: consecutive blocks on one XCD share the q-slice (mask reuse)
  int fid = blockIdx.x;
  int xcd = fid & 7, slot = fid >> 3;
  int h = slot & 15;
  int q0 = (xcd*4 + (slot>>4)) * 64;

  const ushort* Qb = Q + (((size_t)(w*H_ + h))*S_ + q0)*DH_;
  const ushort* Kb = K + ((size_t)(w*H_ + h))*S_*DH_;
  const ushort* Vb = Vt + ((size_t)(w*H_ + h))*DH_*S_;

  bf16x8 qf[4][2];                       // Q B-frags, persistent
  #pragma unroll
  for (int qt=0; qt<4; qt++)
    #pragma unroll
    for (int ks=0; ks<2; ks++)
      qf[qt][ks] = *(const bf16x8*)&Qb[(qt*16 + ln)*DH_ + ks*32 + lq*8];

  f32x4 of[4][4];                        // O^T accum [d-tile][q-tile]
  #pragma unroll
  for (int i=0;i<4;i++)
    #pragma unroll
    for(int j=0;j<4;j++) of[i][j] = zero4();

  int q_sm = w*16 + ln;                  // softmax-phase local q
  int c_sm = lq;                         // softmax-phase kpos chunk-of-8
  const float* mrow0 = mask + (size_t)(q0 + q_sm)*S_;

  for (int kk = 0; kk < S_; kk += 32){
    // ---- S^T = K * Q^T (per-wave batch) ----
    f32x4 sacc[2][4];
    {
      bf16x8 kf[2][2];
      #pragma unroll
      for (int t=0;t<2;t++)
        #pragma unroll
        for (int ks=0;ks<2;ks++)
          kf[t][ks] = *(const bf16x8*)&Kb[(size_t)(kk + t*16 + ln)*DH_ + ks*32 + lq*8];
      #pragma unroll
      for (int t=0;t<2;t++)
        #pragma unroll
        for (int qt=0;qt<4;qt++){
          f32x4 a = __builtin_amdgcn_mfma_f32_16x16x32_bf16(kf[t][0], qf[qt][0], zero4(), 0,0,0);
          sacc[t][qt] = __builtin_amdgcn_mfma_f32_16x16x32_bf16(kf[t][1], qf[qt][1], a, 0,0,0);
        }
    }
    // ---- write S^T to LDS (swizzled, conflict-free) ----
    #pragma unroll
    for (int t=0;t<2;t++)
      #pragma unroll
      for (int qt=0;qt<4;qt++){
        int q = qt*16 + ln;
        int kc = t*4 + lq;               // 16B chunk (4 floats)
        *(f32x4*)&Sl[(w*64 + q)*32 + (kc ^ (q & 7))*4] = sacc[t][qt];
      }
    __syncthreads();
    // ---- softmax over batch (4 values per cell, all in-lane) ----
    float sv[4][8], mx[8];
    #pragma unroll
    for (int j=0;j<8;j++) mx[j] = -3.4e38f;
    #pragma unroll
    for (int b2=0;b2<4;b2++){
      int kc0 = 2*c_sm, kc1 = 2*c_sm+1;
      f32x4 s0 = *(const f32x4*)&Sl[(b2*64 + q_sm)*32 + (kc0 ^ (q_sm&7))*4];
      f32x4 s1 = *(const f32x4*)&Sl[(b2*64 + q_sm)*32 + (kc1 ^ (q_sm&7))*4];
      const float* mp = mrow0 + (size_t)b2*S_*S_ + kk + c_sm*8;
      float4 m0 = *(const float4*)mp;
      float4 m1 = *(const float4*)(mp+4);
      float qs[8] = {s0.x,s0.y,s0.z,s0.w,s1.x,s1.y,s1.z,s1.w};
      float mm[8] = {m0.x,m0.y,m0.z,m0.w,m1.x,m1.y,m1.z,m1.w};
      #pragma unroll
      for (int j=0;j<8;j++){
        // match ref rounding: t2 = fl(m*-1e9); s = fl(qk*0.125 + t2); *0.125 exact
        float t2 = __fmul_rn(mm[j], -1e9f);
        float s  = __fadd_rn(qs[j]*0.125f, t2);
        sv[b2][j] = s;
        mx[j] = fmaxf(mx[j], s);
      }
    }
    float e[4][8];
    #pragma unroll
    for (int j=0;j<8;j++){
      float e0 = __expf(sv[0][j]-mx[j]);
      float e1 = __expf(sv[1][j]-mx[j]);
      float e2 = __expf(sv[2][j]-mx[j]);
      float e3 = __expf(sv[3][j]-mx[j]);
      float inv = 1.0f / ((e0+e1)+(e2+e3));
      e[0][j]=e0*inv; e[1][j]=e1*inv; e[2][j]=e2*inv; e[3][j]=e3*inv;
    }
    #pragma unroll
    for (int b2=0;b2<4;b2++){
      uint4 p;
      p.x = pack2(e[b2][0], e[b2][1]);
      p.y = pack2(e[b2][2], e[b2][3]);
      p.z = pack2(e[b2][4], e[b2][5]);
      p.w = pack2(e[b2][6], e[b2][7]);
      int sl = c_sm ^ ((q_sm>>1)&3);
      *(uint4*)&Pl[(b2*64 + q_sm)*32 + sl*8] = p;
    }
    __syncthreads();
    // ---- O^T += V^T * P^T (per-wave batch) ----
    bf16x8 vf[4], pf[4];
    #pragma unroll
    for (int dt=0;dt<4;dt++)
      vf[dt] = *(const bf16x8*)&Vb[(size_t)(dt*16 + ln)*S_ + kk + lq*8];
    #pragma unroll
    for (int qt=0;qt<4;qt++){
      int q = qt*16 + ln;
      int sl = lq ^ ((q>>1)&3);
      pf[qt] = *(const bf16x8*)&Pl[(w*64 + q)*32 + sl*8];
    }
    #pragma unroll
    for (int dt=0;dt<4;dt++)
      #pragma unroll
      for (int qt=0;qt<4;qt++)
        of[dt][qt] = __builtin_amdgcn_mfma_f32_16x16x32_bf16(vf[dt], pf[qt], of[dt][qt], 0,0,0);
  }

  // ---- epilogue: O[b, q0+q, h*64+d], 4 consecutive d per lane ----
  float* ob = out + ((size_t)w*S_ + q0)*DM_ + h*DH_;
  #pragma unroll
  for (int dt=0;dt<4;dt++)
    #pragma unroll
    for (int qt=0;qt<4;qt++){
      int q = qt*16 + ln;
      int d = dt*16 + lq*4;
      *(f32x4*)&ob[(size_t)q*DM_ + d] = of[dt][qt];
    }
}

// ---------------------------------------------------------------------------
extern "C" void kernel_launch(void* const* d_in, const int* in_sizes, int n_in,
                              void* d_out, int out_size, void* d_ws, size_t ws_size,
                              hipStream_t stream)
{
  const float* xq   = (const float*)d_in[0];
  const float* xk   = (const float*)d_in[1];
  const float* xv   = (const float*)d_in[2];
  const float* mask = (const float*)d_in[3];
  const float* Wq   = (const float*)d_in[4];
  const float* bq   = (const float*)d_in[5];
  const float* Wk   = (const float*)d_in[6];
  const float* bk   = (const float*)d_in[7];
  const float* Wv   = (const float*)d_in[8];
  const float* bv   = (const float*)d_in[9];
  float* out = (float*)d_out;

  char* ws = (char*)d_ws;                      // 54 MB used
  ushort* Wtq = (ushort*)(ws);                 // 2 MB each
  ushort* Wtk = (ushort*)(ws + (2ull<<20));
  ushort* Wtv = (ushort*)(ws + (4ull<<20));
  ushort* Qb  = (ushort*)(ws + (6ull<<20));    // 16 MB each
  ushort* Kb  = (ushort*)(ws + (22ull<<20));
  ushort* Vtb = (ushort*)(ws + (38ull<<20));

  dim3 tgrid(32, 32);
  wtrans<<<tgrid, 256, 0, stream>>>(Wq, Wtq);
  wtrans<<<tgrid, 256, 0, stream>>>(Wk, Wtk);
  wtrans<<<tgrid, 256, 0, stream>>>(Wv, Wtv);

  dim3 ggrid(64, 8);
  gemm_proj<0><<<ggrid, 256, 0, stream>>>(xq, Wtq, bq, Qb);
  gemm_proj<0><<<ggrid, 256, 0, stream>>>(xk, Wtk, bk, Kb);
  gemm_proj<1><<<ggrid, 256, 0, stream>>>(xv, Wtv, bv, Vtb);

  attn<<<512, 256, 0, stream>>>(Qb, Kb, Vtb, mask, out);
}